// Round 9
// baseline (260.314 us; speedup 1.0000x reference)
//
#include <hip/hip_runtime.h>
#include <hip/hip_fp16.h>

// v8: K=4 software pipeline with fused fill/accum overlap.
//   upcnt : ONE kernel = upack (u_phys -> fp16x3 in 8B/node, 8MB gather
//           target) + count of all 4 chunks (one conn pass, 4 LDS hists).
//   scan4 : 1 block; segmented scan of all 4 chunks' bucket counts ->
//           base_c[NBC+1], cursor_c (padded), zero accSlots.
//   fill0 : chunk0 -> arena0 (LDS bucket sort, contiguous nt flush).
//   mid x3: fused dispatch: blocks [0,NT) run fill(chunk c)->arena[c&1],
//           blocks [NT,NT+NBc) run accum(chunk c-1)<-arena[(c-1)&1].
//           Disjoint arenas -> no race; accum hides in fill's shadow.
//   accum : chunk3 replay + fused masked loss (int Q13 LDS atomics, native
//           ds_add -- v7's fix).  final: 1-wave reduce.
// Records: 8B {fx16,fy16 | local12,fz16}. Fused ws = ~30.02 MB (same as the
// proven-fit v6 K=2 layout); serial single-arena fallback = 22 MB.

#define SPANC  4096          // nodes per coarse bucket
#define NBC    256           // max coarse buckets
#define CURP   4             // ints per padded cursor slot (16 B)
#define FTH    1024
#define FBE    2048          // elems per fill tile (4096 records)
#define CB     96            // count blocks
#define NCHUNK 4
#define BASEI  272           // ints per base row (1088 B, 64B-aligned)
#define QSCALE 8192.0f
#define QINV   1.220703125e-4f

#define SMEM_BYTES 49408
// fill carve: slab 32768 | sbk 4096 | hist 1024 | boff 1024 | ast 1024 | wsum 64
#define FO_SLAB 0
#define FO_SBK  32768
#define FO_HIST 36864
#define FO_BOFF 37888
#define FO_AST  38912
#define FO_WSUM 39936
// accum carve: tile 49152 | sn 128 | sd 128
#define AO_TILE 0
#define AO_SN   49152
#define AO_SD   49280

__device__ __forceinline__ uint2 packrec(float fx, float fy, float fz, int local) {
    unsigned short hx = __half_as_ushort(__float2half(fx));
    unsigned short hy = __half_as_ushort(__float2half(fy));
    unsigned short hz = __half_as_ushort(__float2half(fz));
    return make_uint2(((unsigned)hy << 16) | hx, ((unsigned)local << 16) | hz);
}

// 1024-thread inclusive scan. Call sites separated by __syncthreads().
__device__ __forceinline__ int block_incl_scan(int v, int* wsum, int lane, int wv) {
    #pragma unroll
    for (int off = 1; off < 64; off <<= 1) {
        int t = __shfl_up(v, off, 64);
        if (lane >= off) v += t;
    }
    if (lane == 63) wsum[wv] = v;
    __syncthreads();
    if (wv == 0) {
        int w = (lane < 16) ? wsum[lane] : 0;
        #pragma unroll
        for (int off = 1; off < 16; off <<= 1) {
            int t = __shfl_up(w, off, 64);
            if (lane >= off) w += t;
        }
        if (lane < 16) wsum[lane] = w;
    }
    __syncthreads();
    return v + ((wv > 0) ? wsum[wv - 1] : 0);
}

// ---------------- fused upack + count(all chunks) ----------------
__global__ void __launch_bounds__(1024)
upcnt_kernel(const float* __restrict__ pred, const float* __restrict__ u_c,
             const float* __restrict__ theta_c, uint2* __restrict__ up,
             int N, int upG,
             const long long* __restrict__ conn, int* __restrict__ rows,
             int E, int CE) {
    __shared__ int h[NCHUNK][NBC];   // 4 KB
    int tid = threadIdx.x;
    int bid = blockIdx.x;

    if (bid < upG) {                 // ---- upack branch (no barriers) ----
        int i = bid * 1024 + tid;
        if (i < N) {
            float uc = u_c[0], tc = theta_c[0];
            float x = __builtin_nontemporal_load(&pred[3 * i + 0]) * uc;
            float y = __builtin_nontemporal_load(&pred[3 * i + 1]) * uc;
            float z = __builtin_nontemporal_load(&pred[3 * i + 2]) * tc;
            unsigned hx = __half_as_ushort(__float2half(x));
            unsigned hy = __half_as_ushort(__float2half(y));
            unsigned hz = __half_as_ushort(__float2half(z));
            up[i] = make_uint2((hy << 16) | hx, hz);  // temporal: L2-resident
        }
        return;
    }

    // ---- count branch: one conn pass, classify into 4 chunks ----
    int blk = bid - upG;
    h[tid >> 8][tid & 255] = 0;      // 1024 = 4*256
    __syncthreads();
    int stride = CB * 1024;
    int ce2 = 2 * CE, ce3 = 3 * CE;
    for (int e = blk * 1024 + tid; e < E; e += stride) {
        long long v = __builtin_nontemporal_load(conn + e);
        int na = (int)(unsigned)((unsigned long long)v & 0xFFFFFFFFull);
        int nb = (int)(unsigned)((unsigned long long)v >> 32);
        int c = (e >= ce2) ? ((e >= ce3) ? 3 : 2) : ((e >= CE) ? 1 : 0);
        atomicAdd(&h[c][na >> 12], 1);
        atomicAdd(&h[c][nb >> 12], 1);
    }
    __syncthreads();
    int c = tid >> 8, b = tid & 255;
    __builtin_nontemporal_store(h[c][b], &rows[(c * CB + blk) * NBC + b]);
}

// ---------------- segmented scan for all chunks ----------------
__global__ void __launch_bounds__(1024)
scan4_kernel(const int* __restrict__ rows, int* __restrict__ cursors,
             int* __restrict__ bases, double* __restrict__ accSlots) {
    __shared__ int wsum[16];
    __shared__ int segend[NCHUNK];
    int tid = threadIdx.x, lane = tid & 63, wv = tid >> 6;
    int c = tid >> 8, b = tid & 255;
    int v = 0;
    #pragma unroll 4
    for (int r = 0; r < CB; ++r) v += rows[(c * CB + r) * NBC + b];
    int incl = block_incl_scan(v, wsum, lane, wv);
    if (b == 255) segend[c] = incl;
    __syncthreads();
    int segoff = (c > 0) ? segend[c - 1] : 0;
    int inclSeg = incl - segoff;
    int* base_c = bases + c * BASEI;
    base_c[b + 1] = inclSeg;
    if (b == 0) base_c[0] = 0;
    cursors[(c * NBC + b) * CURP] = inclSeg - v;   // exclusive start
    if (tid < 512) accSlots[tid] = 0.0;
}

// ---------------- fill body ----------------
__device__ __forceinline__ void fill_body(
    char* smem,
    const long long* __restrict__ conn,
    const uint2* __restrict__ upk,
    const float* __restrict__ len,
    const float* __restrict__ pE,
    const float* __restrict__ pA,
    const float* __restrict__ pI,
    const float* __restrict__ dir,
    uint2* __restrict__ arena,
    int* __restrict__ cursor,
    int cs, int ce, int bid) {
    uint2*         slab   = (uint2*)(smem + FO_SLAB);
    unsigned char* sbk    = (unsigned char*)(smem + FO_SBK);
    int*           hist   = (int*)(smem + FO_HIST);
    int*           boff   = (int*)(smem + FO_BOFF);
    int*           astart = (int*)(smem + FO_AST);
    int*           wsum   = (int*)(smem + FO_WSUM);

    int tid = threadIdx.x, lane = tid & 63, wv = tid >> 6;
    if (tid < NBC) hist[tid] = 0;
    __syncthreads();

    int bs = cs + bid * FBE;
    int be = bs + FBE; if (be > ce) be = ce;

    unsigned sv[4];
    uint2    rc[4];

    #pragma unroll
    for (int j = 0; j < 2; ++j) {
        int e = bs + j * FTH + tid;
        unsigned sa = 0xFFFFFFFFu, sb = 0xFFFFFFFFu;
        if (e < be) {
            long long cv = __builtin_nontemporal_load(conn + e);
            int na = (int)(unsigned)((unsigned long long)cv & 0xFFFFFFFFull);
            int nb = (int)(unsigned)((unsigned long long)cv >> 32);

            uint2 ua = upk[na];           // 8B aligned gather
            uint2 ub = upk[nb];

            float c  = __builtin_nontemporal_load(&dir[3 * e + 0]);
            float s  = __builtin_nontemporal_load(&dir[3 * e + 2]);
            float L  = __builtin_nontemporal_load(&len[e]);
            float Ee = __builtin_nontemporal_load(&pE[e]);
            float EA = Ee * __builtin_nontemporal_load(&pA[e]);
            float EI = Ee * __builtin_nontemporal_load(&pI[e]);

            float a0 = __half2float(__ushort_as_half((unsigned short)(ua.x & 0xFFFFu)));
            float a1 = __half2float(__ushort_as_half((unsigned short)(ua.x >> 16)));
            float a2 = __half2float(__ushort_as_half((unsigned short)(ua.y & 0xFFFFu)));
            float b0 = __half2float(__ushort_as_half((unsigned short)(ub.x & 0xFFFFu)));
            float b1 = __half2float(__ushort_as_half((unsigned short)(ub.x >> 16)));
            float b2 = __half2float(__ushort_as_half((unsigned short)(ub.y & 0xFFFFu)));

            float u_A  =  c * a0 + s * a1;
            float w_A  = -s * a0 + c * a1;
            float th_A = -a2;
            float u_B  =  c * b0 + s * b1;
            float w_B  = -s * b0 + c * b1;
            float th_B = -b2;

            float invL  = 1.0f / L;
            float ea_l  = EA * invL;             // AXIAL_WEIGHT = 1.0
            float ei_l  = EI * invL;
            float ei_l2 = ei_l  * invL;
            float ei_l3 = ei_l2 * invL;

            float dw = w_A - w_B;
            float f0 = ea_l * (u_A - u_B);
            float f1 = 12.0f * ei_l3 * dw + 6.0f * ei_l2 * (th_A + th_B);
            float f2 = 6.0f * ei_l2 * dw + 4.0f * ei_l * th_A + 2.0f * ei_l * th_B;
            float f5 = 6.0f * ei_l2 * dw + 2.0f * ei_l * th_A + 4.0f * ei_l * th_B;

            float fA0 = c * f0 - s * f1;
            float fA1 = s * f0 + c * f1;

            int bkA = na >> 12;
            int rA  = atomicAdd(&hist[bkA], 1);
            sa = ((unsigned)rA << 8) | (unsigned)bkA;
            rc[2 * j + 0] = packrec(fA0, fA1, -f2, na & 4095);

            int bkB = nb >> 12;
            int rB  = atomicAdd(&hist[bkB], 1);
            sb = ((unsigned)rB << 8) | (unsigned)bkB;
            rc[2 * j + 1] = packrec(-fA0, -fA1, -f5, nb & 4095);
        }
        sv[2 * j + 0] = sa;
        sv[2 * j + 1] = sb;
    }
    __syncthreads();

    int h = (tid < NBC) ? hist[tid] : 0;
    if (tid < NBC && h) astart[tid] = atomicAdd(&cursor[tid * CURP], h);
    int iT = block_incl_scan(h, wsum, lane, wv);   // internal syncs order astart
    if (tid < NBC) boff[tid] = iT - h;
    __syncthreads();

    #pragma unroll
    for (int r = 0; r < 4; ++r) {
        unsigned s2 = sv[r];
        if (s2 != 0xFFFFFFFFu) {
            int bk = (int)(s2 & 255u);
            int rk = (int)(s2 >> 8);
            int slot = boff[bk] + rk;
            slab[slot] = rc[r];
            sbk[slot]  = (unsigned char)bk;
        }
    }
    __syncthreads();

    int tot = boff[NBC - 1] + hist[NBC - 1];
    for (int i = tid; i < tot; i += FTH) {
        int bk = sbk[i];
        uint2 r2 = slab[i];
        unsigned long long v = ((unsigned long long)r2.y << 32) | (unsigned long long)r2.x;
        __builtin_nontemporal_store(v,
            (unsigned long long*)&arena[astart[bk] + (i - boff[bk])]);
    }
}

// ---------------- accum body ----------------
__device__ __forceinline__ void accum_body(
    char* smem,
    const unsigned long long* __restrict__ arena,
    const int* __restrict__ base,
    const float* __restrict__ Fext,
    const float* __restrict__ bcd,
    const float* __restrict__ bcr,
    double* __restrict__ accSlots,
    unsigned short* __restrict__ fint16,
    int N, int isFirst, int isLast, int b) {
    int*    tile = (int*)(smem + AO_TILE);     // Q13 fixed-point
    double* sn   = (double*)(smem + AO_SN);
    double* sd   = (double*)(smem + AO_SD);

    int tid = threadIdx.x, lane = tid & 63, wv = tid >> 6;
    int nodeLo = b * SPANC;
    int gBase = nodeLo * 3;
    int gMax  = 3 * N;

    if (isFirst) {
        for (int i = tid; i < SPANC * 3; i += FTH) tile[i] = 0;
    } else {
        for (int i = tid; i < SPANC * 3; i += FTH) {
            int g = gBase + i;
            tile[i] = (g < gMax)
                ? __float2int_rn(__half2float(__ushort_as_half(
                      __builtin_nontemporal_load(&fint16[g]))) * QSCALE)
                : 0;
        }
    }
    __syncthreads();

    int s0 = base[b];
    int s1 = base[b + 1];
    for (int i = s0 + tid; i < s1; i += FTH) {
        unsigned long long rv = __builtin_nontemporal_load(arena + i);
        unsigned lo = (unsigned)(rv & 0xFFFFFFFFull);
        unsigned hi = (unsigned)(rv >> 32);
        float fx = __half2float(__ushort_as_half((unsigned short)(lo & 0xFFFFu)));
        float fy = __half2float(__ushort_as_half((unsigned short)(lo >> 16)));
        float fz = __half2float(__ushort_as_half((unsigned short)(hi & 0xFFFFu)));
        int local = (int)(hi >> 16);
        atomicAdd(&tile[local * 3 + 0], __float2int_rn(fx * QSCALE));
        atomicAdd(&tile[local * 3 + 1], __float2int_rn(fy * QSCALE));
        atomicAdd(&tile[local * 3 + 2], __float2int_rn(fz * QSCALE));
    }
    __syncthreads();

    if (!isLast) {
        for (int i = tid; i < SPANC * 3; i += FTH) {
            int g = gBase + i;
            if (g < gMax)
                __builtin_nontemporal_store(
                    __half_as_ushort(__float2half((float)tile[i] * QINV)),
                    &fint16[g]);
        }
        return;
    }

    int spanCnt = N - nodeLo;
    if (spanCnt > SPANC) spanCnt = SPANC;

    double num = 0.0, den = 0.0;
    for (int l = tid; l < spanCnt; l += FTH) {
        int n = nodeLo + l;
        float md = 1.0f - __builtin_nontemporal_load(&bcd[n]);
        float mr = 1.0f - __builtin_nontemporal_load(&bcr[n]);
        float e0 = __builtin_nontemporal_load(&Fext[3 * n + 0]);
        float e1 = __builtin_nontemporal_load(&Fext[3 * n + 1]);
        float e2 = __builtin_nontemporal_load(&Fext[3 * n + 2]);
        float t0 = (float)tile[l * 3 + 0] * QINV;
        float t1 = (float)tile[l * 3 + 1] * QINV;
        float t2 = (float)tile[l * 3 + 2] * QINV;
        float r0 = (t0 - e0) * md;
        float r1 = (t1 - e1) * md;
        float r2 = (t2 - e2) * mr;
        float g0 = e0 * md;
        float g1 = e1 * md;
        float g2 = e2 * mr;
        num += (double)r0 * r0 + (double)r1 * r1 + (double)r2 * r2;
        den += (double)g0 * g0 + (double)g1 * g1 + (double)g2 * g2;
    }
    #pragma unroll
    for (int off = 32; off > 0; off >>= 1) {
        num += __shfl_down(num, off, 64);
        den += __shfl_down(den, off, 64);
    }
    if (lane == 0) { sn[wv] = num; sd[wv] = den; }
    __syncthreads();
    if (tid == 0) {
        double tn = 0.0, td = 0.0;
        #pragma unroll
        for (int w = 0; w < 16; ++w) { tn += sn[w]; td += sd[w]; }
        double* slot = accSlots + (size_t)(b & 63) * 8;
        atomicAdd(&slot[0], tn);
        atomicAdd(&slot[1], td);
    }
}

// ---------------- kernels ----------------
__global__ void __launch_bounds__(1024)
fill_kernel(const long long* __restrict__ conn, const uint2* __restrict__ upk,
            const float* __restrict__ len, const float* __restrict__ pE,
            const float* __restrict__ pA, const float* __restrict__ pI,
            const float* __restrict__ dir, uint2* __restrict__ arena,
            int* __restrict__ cursor, int cs, int ce) {
    __shared__ __align__(16) char smem[SMEM_BYTES];
    fill_body(smem, conn, upk, len, pE, pA, pI, dir, arena, cursor, cs, ce,
              blockIdx.x);
}

__global__ void __launch_bounds__(1024)
accum_kernel(const unsigned long long* __restrict__ arena,
             const int* __restrict__ base, const float* __restrict__ Fext,
             const float* __restrict__ bcd, const float* __restrict__ bcr,
             double* __restrict__ accSlots, unsigned short* __restrict__ fint16,
             int N, int isFirst, int isLast) {
    __shared__ __align__(16) char smem[SMEM_BYTES];
    accum_body(smem, arena, base, Fext, bcd, bcr, accSlots, fint16, N,
               isFirst, isLast, blockIdx.x);
}

__global__ void __launch_bounds__(1024)
mid_kernel(const long long* __restrict__ conn, const uint2* __restrict__ upk,
           const float* __restrict__ len, const float* __restrict__ pE,
           const float* __restrict__ pA, const float* __restrict__ pI,
           const float* __restrict__ dir,
           uint2* __restrict__ arenaF, int* __restrict__ cursorF,
           int csF, int ceF, int NTF,
           const unsigned long long* __restrict__ arenaA,
           const int* __restrict__ baseA,
           const float* __restrict__ Fext, const float* __restrict__ bcd,
           const float* __restrict__ bcr, double* __restrict__ accSlots,
           unsigned short* __restrict__ fint16, int N, int isFirstA) {
    __shared__ __align__(16) char smem[SMEM_BYTES];
    if ((int)blockIdx.x < NTF)
        fill_body(smem, conn, upk, len, pE, pA, pI, dir, arenaF, cursorF,
                  csF, ceF, blockIdx.x);
    else
        accum_body(smem, arenaA, baseA, Fext, bcd, bcr, accSlots, fint16, N,
                   isFirstA, 0, blockIdx.x - NTF);
}

__global__ void final_kernel(const double* __restrict__ accSlots,
                             float* __restrict__ out) {
    int t = threadIdx.x;   // 64 threads
    double n = accSlots[t * 8 + 0];
    double d = accSlots[t * 8 + 1];
    #pragma unroll
    for (int off = 32; off > 0; off >>= 1) {
        n += __shfl_down(n, off, 64);
        d += __shfl_down(d, off, 64);
    }
    if (t == 0) {
        if (d < 1e-30) d = 1e-30;
        out[0] = (float)(n / d);
    }
}

static inline size_t align256(size_t x) { return (x + 255) & ~(size_t)255; }

extern "C" void kernel_launch(void* const* d_in, const int* in_sizes, int n_in,
                              void* d_out, int out_size, void* d_ws, size_t ws_size,
                              hipStream_t stream) {
    const float* pred    = (const float*)d_in[0];
    const float* u_c     = (const float*)d_in[1];
    const float* theta_c = (const float*)d_in[2];
    const float* len     = (const float*)d_in[3];
    const float* pE      = (const float*)d_in[4];
    const float* pA      = (const float*)d_in[5];
    const float* pI      = (const float*)d_in[6];
    const float* dir     = (const float*)d_in[7];
    const float* Fext    = (const float*)d_in[8];
    const float* bcd     = (const float*)d_in[9];
    const float* bcr     = (const float*)d_in[10];
    const long long* conn = (const long long*)d_in[11];

    int N = in_sizes[0] / 3;
    int E = in_sizes[3];
    int NBc = (N + SPANC - 1) / SPANC;           // <= NBC
    int CE  = (E + NCHUNK - 1) / NCHUNK;
    int nCh = (E + CE - 1) / CE;
    int upG = (N + 1023) / 1024;

    // Workspace layout:
    //   0       accSlots  4096 B
    //   4096    cursors   NCHUNK*NBC*CURP*4 = 16384 B
    //   20480   bases     NCHUNK*BASEI*4    = 4352 B
    //   oU      upack     8*N B
    //   oFint   fp16 partial F_int 6*N B
    //   oA0     arena0 (rows[NCHUNK][CB][NBC] aliases head, consumed by scan4)
    //   oA1     arena1 (fused mode only)
    size_t oCur  = 4096;
    size_t oBase = oCur + (size_t)NCHUNK * NBC * CURP * 4;   // 20480
    size_t oU    = align256(oBase + (size_t)NCHUNK * BASEI * 4);
    size_t oFint = align256(oU + (size_t)N * 8);
    size_t oA0   = align256(oFint + (size_t)3 * N * 2);
    size_t arenaB = (size_t)2 * CE * 8;
    size_t rowsB  = (size_t)NCHUNK * CB * NBC * 4;
    size_t a0B    = (arenaB > rowsB) ? arenaB : rowsB;
    size_t oA1    = align256(oA0 + a0B);
    int fused = (oA1 + arenaB) <= ws_size;

    double*             accSlots = (double*)d_ws;
    int*                cursors  = (int*)((char*)d_ws + oCur);
    int*                bases    = (int*)((char*)d_ws + oBase);
    uint2*              upk      = (uint2*)((char*)d_ws + oU);
    unsigned short*     fint16   = (unsigned short*)((char*)d_ws + oFint);
    uint2*              arena0   = (uint2*)((char*)d_ws + oA0);
    uint2*              arena1   = (uint2*)((char*)d_ws + oA1);
    int*                rows     = (int*)arena0;   // alias, pre-fill only

    upcnt_kernel<<<upG + CB, 1024, 0, stream>>>(
        pred, u_c, theta_c, upk, N, upG, conn, rows, E, CE);
    scan4_kernel<<<1, 1024, 0, stream>>>(rows, cursors, bases, accSlots);

    if (fused) {
        // chunk0 fill
        {
            int cs = 0, ce = (CE < E) ? CE : E;
            int NT = (ce - cs + FBE - 1) / FBE;
            fill_kernel<<<NT, FTH, 0, stream>>>(
                conn, upk, len, pE, pA, pI, dir,
                arena0, cursors + 0, 0, ce);
        }
        for (int c = 1; c < nCh; ++c) {
            int cs = c * CE;
            int ce = cs + CE; if (ce > E) ce = E;
            int NT = (ce - cs + FBE - 1) / FBE;
            uint2* aF = (c & 1) ? arena1 : arena0;
            const unsigned long long* aA = (const unsigned long long*)
                (((c - 1) & 1) ? arena1 : arena0);
            mid_kernel<<<NT + NBc, FTH, 0, stream>>>(
                conn, upk, len, pE, pA, pI, dir,
                aF, cursors + (size_t)c * NBC * CURP, cs, ce, NT,
                aA, bases + (size_t)(c - 1) * BASEI,
                Fext, bcd, bcr, accSlots, fint16, N, (c - 1) == 0);
        }
        {
            int last = nCh - 1;
            const unsigned long long* aA = (const unsigned long long*)
                ((last & 1) ? arena1 : arena0);
            accum_kernel<<<NBc, FTH, 0, stream>>>(
                aA, bases + (size_t)last * BASEI,
                Fext, bcd, bcr, accSlots, fint16, N, last == 0, 1);
        }
    } else {
        // serial fallback: single arena, same kernels
        for (int c = 0; c < nCh; ++c) {
            int cs = c * CE;
            int ce = cs + CE; if (ce > E) ce = E;
            int NT = (ce - cs + FBE - 1) / FBE;
            fill_kernel<<<NT, FTH, 0, stream>>>(
                conn, upk, len, pE, pA, pI, dir,
                arena0, cursors + (size_t)c * NBC * CURP, cs, ce);
            accum_kernel<<<NBc, FTH, 0, stream>>>(
                (const unsigned long long*)arena0, bases + (size_t)c * BASEI,
                Fext, bcd, bcr, accSlots, fint16, N, c == 0, c == nCh - 1);
        }
    }

    final_kernel<<<1, 64, 0, stream>>>(accSlots, (float*)d_out);
}

// Round 11
// 236.789 us; speedup vs baseline: 1.0993x; 1.0993x over previous
//
#include <hip/hip_runtime.h>
#include <hip/hip_fp16.h>

// v9 = v7 (223.5us champion) + safe launch fusion. K=2 serial pipeline with
// machine-full 489-block fills (v8's K=4 fused overlap REGRESSED: half-width
// latency-bound fills + doubled fint traffic).
//   upcnt : upack (u_phys -> fp16x3, 8B/node, 8MB gather target) runs
//           CONCURRENTLY with one full-conn count pass (4-way chunk classify).
//   scan4 : 1 block; segmented scan of all chunk bucket counts -> bases,
//           cursors; zeroes accSlots.
//   fill  : per chunk; 2048-elem tiles, ONE-stage LDS bucket sort, coalesced
//           nt flush into contiguous per-bucket arena runs (~16 rec).
//   accum : per chunk; block = 4096-node bucket, 48KB int Q13 tile, native
//           ds_add atomics (v7 fix); fp16 partial across chunks; fused loss.
//   final : 1-wave reduce.
// Records: 8B {fx16,fy16 | local12,fz16}. Ladder K=2 30.03MB / K=3 24.7MB.

#define SPANC  4096          // nodes per coarse bucket
#define NBC    256           // max coarse buckets
#define CURP   4             // ints per padded cursor slot (16 B)
#define FTH    1024
#define FBE    2048          // elems per fill tile (4096 records)
#define CB     96            // count blocks
#define NCHMAX 4
#define BASEI  272           // ints per base row
#define QSCALE 8192.0f
#define QINV   1.220703125e-4f

__device__ __forceinline__ uint2 packrec(float fx, float fy, float fz, int local) {
    unsigned short hx = __half_as_ushort(__float2half(fx));
    unsigned short hy = __half_as_ushort(__float2half(fy));
    unsigned short hz = __half_as_ushort(__float2half(fz));
    return make_uint2(((unsigned)hy << 16) | hx, ((unsigned)local << 16) | hz);
}

// 1024-thread inclusive scan. Call sites separated by __syncthreads().
__device__ __forceinline__ int block_incl_scan(int v, int* wsum, int lane, int wv) {
    #pragma unroll
    for (int off = 1; off < 64; off <<= 1) {
        int t = __shfl_up(v, off, 64);
        if (lane >= off) v += t;
    }
    if (lane == 63) wsum[wv] = v;
    __syncthreads();
    if (wv == 0) {
        int w = (lane < 16) ? wsum[lane] : 0;
        #pragma unroll
        for (int off = 1; off < 16; off <<= 1) {
            int t = __shfl_up(w, off, 64);
            if (lane >= off) w += t;
        }
        if (lane < 16) wsum[lane] = w;
    }
    __syncthreads();
    return v + ((wv > 0) ? wsum[wv - 1] : 0);
}

// ---------------- fused upack + count(all chunks) ----------------
__global__ void __launch_bounds__(1024)
upcnt_kernel(const float* __restrict__ pred, const float* __restrict__ u_c,
             const float* __restrict__ theta_c, uint2* __restrict__ up,
             int N, int upG,
             const long long* __restrict__ conn, int* __restrict__ rows,
             int E, int CE) {
    __shared__ int h[NCHMAX][NBC];   // 4 KB
    int tid = threadIdx.x;
    int bid = blockIdx.x;

    if (bid < upG) {                 // ---- upack branch (no barriers) ----
        int i = bid * 1024 + tid;
        if (i < N) {
            float uc = u_c[0], tc = theta_c[0];
            float x = __builtin_nontemporal_load(&pred[3 * i + 0]) * uc;
            float y = __builtin_nontemporal_load(&pred[3 * i + 1]) * uc;
            float z = __builtin_nontemporal_load(&pred[3 * i + 2]) * tc;
            unsigned hx = __half_as_ushort(__float2half(x));
            unsigned hy = __half_as_ushort(__float2half(y));
            unsigned hz = __half_as_ushort(__float2half(z));
            up[i] = make_uint2((hy << 16) | hx, hz);  // temporal: L2-resident
        }
        return;
    }

    // ---- count branch: one conn pass, classify into up to 4 chunks ----
    int blk = bid - upG;
    h[tid >> 8][tid & 255] = 0;      // 1024 = 4*256
    __syncthreads();
    int stride = CB * 1024;
    int ce2 = 2 * CE, ce3 = 3 * CE;
    for (int e = blk * 1024 + tid; e < E; e += stride) {
        long long v = __builtin_nontemporal_load(conn + e);
        int na = (int)(unsigned)((unsigned long long)v & 0xFFFFFFFFull);
        int nb = (int)(unsigned)((unsigned long long)v >> 32);
        int c = (e >= ce2) ? ((e >= ce3) ? 3 : 2) : ((e >= CE) ? 1 : 0);
        atomicAdd(&h[c][na >> 12], 1);
        atomicAdd(&h[c][nb >> 12], 1);
    }
    __syncthreads();
    int c = tid >> 8, b = tid & 255;
    __builtin_nontemporal_store(h[c][b], &rows[(c * CB + blk) * NBC + b]);
}

// ---------------- segmented scan for all chunks ----------------
__global__ void __launch_bounds__(1024)
scan4_kernel(const int* __restrict__ rows, int* __restrict__ cursors,
             int* __restrict__ bases, double* __restrict__ accSlots) {
    __shared__ int wsum[16];
    __shared__ int segend[NCHMAX];
    int tid = threadIdx.x, lane = tid & 63, wv = tid >> 6;
    int c = tid >> 8, b = tid & 255;
    int v = 0;
    #pragma unroll 4
    for (int r = 0; r < CB; ++r) v += rows[(c * CB + r) * NBC + b];
    int incl = block_incl_scan(v, wsum, lane, wv);
    if (b == 255) segend[c] = incl;
    __syncthreads();
    int segoff = (c > 0) ? segend[c - 1] : 0;
    int inclSeg = incl - segoff;
    int* base_c = bases + c * BASEI;
    base_c[b + 1] = inclSeg;
    if (b == 0) base_c[0] = 0;
    cursors[(c * NBC + b) * CURP] = inclSeg - v;   // exclusive start
    if (tid < 512) accSlots[tid] = 0.0;
}

// ---------------- fill (v7 body verbatim) ----------------
__global__ void __launch_bounds__(1024)
fill_kernel(const long long* __restrict__ conn,
            const uint2* __restrict__ upk,
            const float* __restrict__ len,
            const float* __restrict__ pE,
            const float* __restrict__ pA,
            const float* __restrict__ pI,
            const float* __restrict__ dir,
            uint2* __restrict__ arena,
            int* __restrict__ cursor,
            int cs, int ce) {
    __shared__ uint2         slab[2 * FBE];   // 4096 recs, 32KB
    __shared__ unsigned char sbk [2 * FBE];   // 4KB
    __shared__ int hist [NBC];
    __shared__ int boff [NBC];
    __shared__ int astart[NBC];
    __shared__ int wsum [16];
    // ~39.3KB -> 2 blocks/CU (thread-capped), 32 waves/CU

    int tid = threadIdx.x, lane = tid & 63, wv = tid >> 6;

    if (tid < NBC) hist[tid] = 0;
    __syncthreads();

    int bs = cs + blockIdx.x * FBE;
    int be = bs + FBE; if (be > ce) be = ce;

    unsigned sv[4];   // (rank<<8)|bucket ; 0xFFFFFFFF = none
    uint2    rc[4];

    #pragma unroll
    for (int j = 0; j < 2; ++j) {
        int e = bs + j * FTH + tid;
        unsigned sa = 0xFFFFFFFFu, sb = 0xFFFFFFFFu;
        if (e < be) {
            long long cv = __builtin_nontemporal_load(conn + e);
            int na = (int)(unsigned)((unsigned long long)cv & 0xFFFFFFFFull);
            int nb = (int)(unsigned)((unsigned long long)cv >> 32);

            uint2 ua = upk[na];           // 8B aligned gathers first
            uint2 ub = upk[nb];

            float c  = __builtin_nontemporal_load(&dir[3 * e + 0]);
            float s  = __builtin_nontemporal_load(&dir[3 * e + 2]);
            float L  = __builtin_nontemporal_load(&len[e]);
            float Ee = __builtin_nontemporal_load(&pE[e]);
            float EA = Ee * __builtin_nontemporal_load(&pA[e]);
            float EI = Ee * __builtin_nontemporal_load(&pI[e]);

            float a0 = __half2float(__ushort_as_half((unsigned short)(ua.x & 0xFFFFu)));
            float a1 = __half2float(__ushort_as_half((unsigned short)(ua.x >> 16)));
            float a2 = __half2float(__ushort_as_half((unsigned short)(ua.y & 0xFFFFu)));
            float b0 = __half2float(__ushort_as_half((unsigned short)(ub.x & 0xFFFFu)));
            float b1 = __half2float(__ushort_as_half((unsigned short)(ub.x >> 16)));
            float b2 = __half2float(__ushort_as_half((unsigned short)(ub.y & 0xFFFFu)));

            float u_A  =  c * a0 + s * a1;
            float w_A  = -s * a0 + c * a1;
            float th_A = -a2;
            float u_B  =  c * b0 + s * b1;
            float w_B  = -s * b0 + c * b1;
            float th_B = -b2;

            float invL  = 1.0f / L;
            float ea_l  = EA * invL;             // AXIAL_WEIGHT = 1.0
            float ei_l  = EI * invL;
            float ei_l2 = ei_l  * invL;
            float ei_l3 = ei_l2 * invL;

            float dw = w_A - w_B;
            float f0 = ea_l * (u_A - u_B);
            float f1 = 12.0f * ei_l3 * dw + 6.0f * ei_l2 * (th_A + th_B);
            float f2 = 6.0f * ei_l2 * dw + 4.0f * ei_l * th_A + 2.0f * ei_l * th_B;
            float f5 = 6.0f * ei_l2 * dw + 2.0f * ei_l * th_A + 4.0f * ei_l * th_B;

            float fA0 = c * f0 - s * f1;
            float fA1 = s * f0 + c * f1;

            int bkA = na >> 12;
            int rA  = atomicAdd(&hist[bkA], 1);
            sa = ((unsigned)rA << 8) | (unsigned)bkA;
            rc[2 * j + 0] = packrec(fA0, fA1, -f2, na & 4095);

            int bkB = nb >> 12;
            int rB  = atomicAdd(&hist[bkB], 1);
            sb = ((unsigned)rB << 8) | (unsigned)bkB;
            rc[2 * j + 1] = packrec(-fA0, -fA1, -f5, nb & 4095);
        }
        sv[2 * j + 0] = sa;
        sv[2 * j + 1] = sb;
    }
    __syncthreads();

    int h = (tid < NBC) ? hist[tid] : 0;
    if (tid < NBC && h) astart[tid] = atomicAdd(&cursor[tid * CURP], h);
    int iT = block_incl_scan(h, wsum, lane, wv);   // internal syncs order astart
    if (tid < NBC) boff[tid] = iT - h;
    __syncthreads();

    #pragma unroll
    for (int r = 0; r < 4; ++r) {
        unsigned s2 = sv[r];
        if (s2 != 0xFFFFFFFFu) {
            int bk = (int)(s2 & 255u);
            int rk = (int)(s2 >> 8);
            int slot = boff[bk] + rk;
            slab[slot] = rc[r];
            sbk[slot]  = (unsigned char)bk;
        }
    }
    __syncthreads();

    int tot = boff[NBC - 1] + hist[NBC - 1];
    for (int i = tid; i < tot; i += FTH) {
        int bk = sbk[i];
        uint2 r2 = slab[i];
        unsigned long long v = ((unsigned long long)r2.y << 32) | (unsigned long long)r2.x;
        __builtin_nontemporal_store(v,
            (unsigned long long*)&arena[astart[bk] + (i - boff[bk])]);
    }
}

// ---------------- accum (v7 body verbatim, fp16 partial) ----------------
__global__ void __launch_bounds__(1024)
accum_kernel(const unsigned long long* __restrict__ arena,
             const int* __restrict__ base,
             const float* __restrict__ Fext,
             const float* __restrict__ bcd,
             const float* __restrict__ bcr,
             double* __restrict__ accSlots,
             unsigned short* __restrict__ fint16,
             int N, int isFirst, int isLast) {
    __shared__ int tile[SPANC * 3];   // 48KB Q13 fixed-point
    __shared__ double sn[16], sd[16];

    int tid = threadIdx.x, lane = tid & 63, wv = tid >> 6;
    int b = blockIdx.x;
    int nodeLo = b * SPANC;
    int gBase = nodeLo * 3;
    int gMax  = 3 * N;

    if (isFirst) {
        for (int i = tid; i < SPANC * 3; i += FTH) tile[i] = 0;
    } else {
        for (int i = tid; i < SPANC * 3; i += FTH) {
            int g = gBase + i;
            tile[i] = (g < gMax)
                ? __float2int_rn(__half2float(__ushort_as_half(
                      __builtin_nontemporal_load(&fint16[g]))) * QSCALE)
                : 0;
        }
    }
    __syncthreads();

    // dense coalesced replay; native int ds_add atomics
    int s0 = base[b];
    int s1 = base[b + 1];
    for (int i = s0 + tid; i < s1; i += FTH) {
        unsigned long long rv = __builtin_nontemporal_load(arena + i);
        unsigned lo = (unsigned)(rv & 0xFFFFFFFFull);
        unsigned hi = (unsigned)(rv >> 32);
        float fx = __half2float(__ushort_as_half((unsigned short)(lo & 0xFFFFu)));
        float fy = __half2float(__ushort_as_half((unsigned short)(lo >> 16)));
        float fz = __half2float(__ushort_as_half((unsigned short)(hi & 0xFFFFu)));
        int local = (int)(hi >> 16);
        atomicAdd(&tile[local * 3 + 0], __float2int_rn(fx * QSCALE));
        atomicAdd(&tile[local * 3 + 1], __float2int_rn(fy * QSCALE));
        atomicAdd(&tile[local * 3 + 2], __float2int_rn(fz * QSCALE));
    }
    __syncthreads();

    if (!isLast) {
        for (int i = tid; i < SPANC * 3; i += FTH) {
            int g = gBase + i;
            if (g < gMax)
                __builtin_nontemporal_store(
                    __half_as_ushort(__float2half((float)tile[i] * QINV)),
                    &fint16[g]);
        }
        return;
    }

    int spanCnt = N - nodeLo;
    if (spanCnt > SPANC) spanCnt = SPANC;

    double num = 0.0, den = 0.0;
    for (int l = tid; l < spanCnt; l += FTH) {
        int n = nodeLo + l;
        float md = 1.0f - __builtin_nontemporal_load(&bcd[n]);
        float mr = 1.0f - __builtin_nontemporal_load(&bcr[n]);
        float e0 = __builtin_nontemporal_load(&Fext[3 * n + 0]);
        float e1 = __builtin_nontemporal_load(&Fext[3 * n + 1]);
        float e2 = __builtin_nontemporal_load(&Fext[3 * n + 2]);
        float t0 = (float)tile[l * 3 + 0] * QINV;
        float t1 = (float)tile[l * 3 + 1] * QINV;
        float t2 = (float)tile[l * 3 + 2] * QINV;
        float r0 = (t0 - e0) * md;
        float r1 = (t1 - e1) * md;
        float r2 = (t2 - e2) * mr;
        float g0 = e0 * md;
        float g1 = e1 * md;
        float g2 = e2 * mr;
        num += (double)r0 * r0 + (double)r1 * r1 + (double)r2 * r2;
        den += (double)g0 * g0 + (double)g1 * g1 + (double)g2 * g2;
    }
    #pragma unroll
    for (int off = 32; off > 0; off >>= 1) {
        num += __shfl_down(num, off, 64);
        den += __shfl_down(den, off, 64);
    }
    if (lane == 0) { sn[wv] = num; sd[wv] = den; }
    __syncthreads();
    if (tid == 0) {
        double tn = 0.0, td = 0.0;
        #pragma unroll
        for (int w = 0; w < 16; ++w) { tn += sn[w]; td += sd[w]; }
        double* slot = accSlots + (size_t)(b & 63) * 8;
        atomicAdd(&slot[0], tn);
        atomicAdd(&slot[1], td);
    }
}

__global__ void final_kernel(const double* __restrict__ accSlots,
                             float* __restrict__ out) {
    int t = threadIdx.x;   // 64 threads
    double n = accSlots[t * 8 + 0];
    double d = accSlots[t * 8 + 1];
    #pragma unroll
    for (int off = 32; off > 0; off >>= 1) {
        n += __shfl_down(n, off, 64);
        d += __shfl_down(d, off, 64);
    }
    if (t == 0) {
        if (d < 1e-30) d = 1e-30;
        out[0] = (float)(n / d);
    }
}

static inline size_t align256(size_t x) { return (x + 255) & ~(size_t)255; }

extern "C" void kernel_launch(void* const* d_in, const int* in_sizes, int n_in,
                              void* d_out, int out_size, void* d_ws, size_t ws_size,
                              hipStream_t stream) {
    const float* pred    = (const float*)d_in[0];
    const float* u_c     = (const float*)d_in[1];
    const float* theta_c = (const float*)d_in[2];
    const float* len     = (const float*)d_in[3];
    const float* pE      = (const float*)d_in[4];
    const float* pA      = (const float*)d_in[5];
    const float* pI      = (const float*)d_in[6];
    const float* dir     = (const float*)d_in[7];
    const float* Fext    = (const float*)d_in[8];
    const float* bcd     = (const float*)d_in[9];
    const float* bcr     = (const float*)d_in[10];
    const long long* conn = (const long long*)d_in[11];

    int N = in_sizes[0] / 3;
    int E = in_sizes[3];
    int NBc = (N + SPANC - 1) / SPANC;           // <= NBC
    int upG = (N + 1023) / 1024;

    // Workspace layout:
    //   0       accSlots  4096 B
    //   4096    cursors   NCHMAX*NBC*CURP*4 = 16384 B
    //   20480   bases     NCHMAX*BASEI*4    = 4352 B
    //   24832   upack     8*N B
    //   oFint   fp16 partial F_int 6*N B
    //   oA      arena (rows[NCHMAX][CB][NBC] aliases head, consumed by scan4)
    size_t oCur  = 4096;
    size_t oBase = oCur + (size_t)NCHMAX * NBC * CURP * 4;   // 20480
    size_t oU    = align256(oBase + (size_t)NCHMAX * BASEI * 4);
    size_t oFint = align256(oU + (size_t)N * 8);
    size_t oA    = align256(oFint + (size_t)3 * N * 2);
    size_t rowsB = (size_t)NCHMAX * CB * NBC * 4;            // 393216

    // Ladder: K=2 (machine-full 489-block fills) -> K=3 -> K=4
    const int cfgK[3] = {2, 3, 4};
    int K = 4;
    for (int t = 0; t < 3; ++t) {
        size_t chunkE = (size_t)(E + cfgK[t] - 1) / cfgK[t];
        size_t arenaB = 2 * chunkE * 8;
        if (arenaB < rowsB) arenaB = rowsB;
        if (oA + arenaB <= ws_size || t == 2) { K = cfgK[t]; if (oA + arenaB <= ws_size) break; }
    }
    int CE  = (E + K - 1) / K;
    int nCh = (E + CE - 1) / CE;

    double*             accSlots = (double*)d_ws;
    int*                cursors  = (int*)((char*)d_ws + oCur);
    int*                bases    = (int*)((char*)d_ws + oBase);
    uint2*              upk      = (uint2*)((char*)d_ws + oU);
    unsigned short*     fint16   = (unsigned short*)((char*)d_ws + oFint);
    uint2*              arena    = (uint2*)((char*)d_ws + oA);
    int*                rows     = (int*)arena;   // alias, consumed by scan4

    upcnt_kernel<<<upG + CB, 1024, 0, stream>>>(
        pred, u_c, theta_c, upk, N, upG, conn, rows, E, CE);
    scan4_kernel<<<1, 1024, 0, stream>>>(rows, cursors, bases, accSlots);

    for (int c = 0; c < nCh; ++c) {
        int cs = c * CE;
        int ce = cs + CE; if (ce > E) ce = E;
        int NT = (ce - cs + FBE - 1) / FBE;
        fill_kernel<<<NT, FTH, 0, stream>>>(
            conn, upk, len, pE, pA, pI, dir,
            arena, cursors + (size_t)c * NBC * CURP, cs, ce);
        accum_kernel<<<NBc, FTH, 0, stream>>>(
            (const unsigned long long*)arena, bases + (size_t)c * BASEI,
            Fext, bcd, bcr, accSlots, fint16, N, c == 0, c == nCh - 1);
    }

    final_kernel<<<1, 64, 0, stream>>>(accSlots, (float*)d_out);
}